// Round 6
// baseline (119.643 us; speedup 1.0000x reference)
//
#include <hip/hip_runtime.h>
#include <math.h>

#define NUM_E   100000
#define GAMMA_F 12.0f
#define EMB_RANGE_F 0.21875f                       // (12+2)/64
#define INV_TWO_EMB (1.0f / (2.0f * EMB_RANGE_F))  // rev = r * this = phase/(2pi)

typedef float v4f __attribute__((ext_vector_type(4)));
typedef float v2f __attribute__((ext_vector_type(2)));

// ---- packed-f32 VALU (VOP3P): 2 dims per instruction ----
static __device__ __forceinline__ v2f pk_sub(v2f a, v2f b) {
    v2f d;
    asm("v_pk_add_f32 %0, %1, %2 neg_lo:[0,1] neg_hi:[0,1]"
        : "=v"(d) : "v"(a), "v"(b));
    return d;
}
static __device__ __forceinline__ v2f pk_mul(v2f a, v2f b) {
    v2f d;
    asm("v_pk_mul_f32 %0, %1, %2" : "=v"(d) : "v"(a), "v"(b));
    return d;
}
static __device__ __forceinline__ v2f pk_fma(v2f a, v2f b, v2f c) {
    v2f d;
    asm("v_pk_fma_f32 %0, %1, %2, %3" : "=v"(d) : "v"(a), "v"(b), "v"(c));
    return d;
}
static __device__ __forceinline__ float sq2(v2f dx, v2f dy) {
    v2f sq = pk_fma(dy, dy, pk_mul(dx, dx));
    return __builtin_amdgcn_sqrtf(sq.x) + __builtin_amdgcn_sqrtf(sq.y);
}
static __device__ __forceinline__ v2f lo2(v4f v) { return __builtin_shufflevector(v, v, 0, 1); }
static __device__ __forceinline__ v2f hi2(v4f v) { return __builtin_shufflevector(v, v, 2, 3); }

// cross-lane add via DPP (VALU pipe, no DS, no lgkm wait)
// 0xB1 = quad_perm [1,0,3,2] (xor1), 0x4E = quad_perm [2,3,0,1] (xor2),
// 0x141 = row_half_mirror: valid xor4 substitute AFTER xor1+xor2 (verified
// passing in R8-R11).
template <int CTRL>
static __device__ __forceinline__ float dpp_xor_add(float x) {
    int y = __builtin_amdgcn_update_dpp(0, __float_as_int(x), CTRL, 0xF, 0xF, true);
    return x + __int_as_float(y);
}

// full per-entity distance for this lane's 4 batches x 8 dims, reduced over dg
static __device__ __forceinline__ float dist_entity(
        v4f er0, v4f er1, v4f ei0, v4f ei1,
        const v2f RR[4][4], const v2f RI[4][4], int dg) {
    v2f e2[4] = { lo2(er0), hi2(er0), lo2(er1), hi2(er1) };
    v2f i2[4] = { lo2(ei0), hi2(ei0), lo2(ei1), hi2(ei1) };
    float r[4];
#pragma unroll
    for (int kb = 0; kb < 4; ++kb) {
        float s0 = sq2(pk_sub(RR[kb][0], e2[0]), pk_sub(RI[kb][0], i2[0]));
        float s1 = sq2(pk_sub(RR[kb][1], e2[1]), pk_sub(RI[kb][1], i2[1]));
        float s2 = sq2(pk_sub(RR[kb][2], e2[2]), pk_sub(RI[kb][2], i2[2]));
        float s3 = sq2(pk_sub(RR[kb][3], e2[3]), pk_sub(RI[kb][3], i2[3]));
        float v = (s0 + s1) + (s2 + s3);
        v = dpp_xor_add<0xB1>(v);            // xor1
        v = dpp_xor_add<0x4E>(v);            // xor2
        v = dpp_xor_add<0x141>(v);           // xor4 via row_half_mirror
        r[kb] = v;
    }
    float sel = (dg == 0) ? r[0] : (dg == 1) ? r[1]
              : (dg == 2) ? r[2] : r[3];
    return GAMMA_F - sel;
}

#define LOADE(d0, d1, d2, d3, EIDX) do {                         \
    const float* _p = ent + (size_t)(EIDX) * 128 + dg * 8;       \
    d0 = *(const v4f*)(_p);      d1 = *(const v4f*)(_p + 4);     \
    d2 = *(const v4f*)(_p + 64); d3 = *(const v4f*)(_p + 68); } while (0)

// R12 = R11 + FORCED register residency of the rot table.
// R11 diagnosis: VGPR_Count=60 -> the 64-float RR/RI table cannot be resident;
// the compiler's occupancy heuristic (8 waves/SIMD @ <=64 regs) rematerializes
// RR/RI from rot_lds inside the entity loop: ~16 ds_read_b128/entity = ~31us
// of per-CU LDS-pipe occupancy = the whole gap between the ~19us issue floor
// and the measured 49us. Prefetch couldn't help while LDS was the co-limiter.
// Fix: pass each rot v4f through an empty inline-asm identity after the
// one-time LDS read. The values become opaque -> no remat possible -> the
// allocator must keep them in VGPRs (live ~120 <= 128 cap from (256,2)).
// Deliberate trade: 4 waves/SIMD instead of 8, LDS pipe ~idle, VALU+trans
// saturated by a nearly stall-free stream (R11's A/B prefetch retained).
__global__ __launch_bounds__(256, 2) void rotate_dist_fused(
        const int*   __restrict__ facts,
        const float* __restrict__ ent,
        const float* __restrict__ rel,
        float*       __restrict__ out) {
    __shared__ __align__(16) float rot_lds[16 * 64 * 4];   // 16 KB

    const int t    = threadIdx.x;
    const int lane = t & 63;
    const int wv   = t >> 6;            // doubles as kb in the prologue
    const int bg   = lane >> 3;         // batches 4bg..4bg+3
    const int dg   = lane & 7;          // dims 8dg..8dg+7

    // ---- prologue: rot table into LDS (wave wv computes kb=wv slots) ----
    {
        const int b  = bg * 4 + wv;     // this thread's batch row
        const int f0 = facts[b * 3 + 0];
        const int f1 = facts[b * 3 + 1];
        const float* hp = ent + (size_t)f0 * 128 + dg * 8;
        const float* rp = rel + (size_t)f1 * 64  + dg * 8;
        v4f hre0 = *(const v4f*)(hp);
        v4f hre1 = *(const v4f*)(hp + 4);
        v4f him0 = *(const v4f*)(hp + 64);
        v4f him1 = *(const v4f*)(hp + 68);
        v4f ph0  = *(const v4f*)(rp);
        v4f ph1  = *(const v4f*)(rp + 4);
        v4f rr0, rr1, ri0, ri1;
#pragma unroll
        for (int j = 0; j < 4; ++j) {
            float rev0 = ph0[j] * INV_TWO_EMB;       // phase/(2pi) in [-0.5,0.5]
            float s0 = __builtin_amdgcn_sinf(rev0);  // v_sin_f32: revolutions
            float c0 = __builtin_amdgcn_cosf(rev0);
            rr0[j] = hre0[j] * c0 - him0[j] * s0;
            ri0[j] = hre0[j] * s0 + him0[j] * c0;
            float rev1 = ph1[j] * INV_TWO_EMB;
            float s1 = __builtin_amdgcn_sinf(rev1);
            float c1 = __builtin_amdgcn_cosf(rev1);
            rr1[j] = hre1[j] * c1 - him1[j] * s1;
            ri1[j] = hre1[j] * s1 + him1[j] * c1;
        }
        // layout: ((kb*4 + part)*64 + lane)*4 ; parts: re-lo, re-hi, im-lo, im-hi
        float* wbase = rot_lds + (wv * 4) * 256 + lane * 4;
        *(v4f*)(wbase + 0 * 256) = rr0;
        *(v4f*)(wbase + 1 * 256) = rr1;
        *(v4f*)(wbase + 2 * 256) = ri0;
        *(v4f*)(wbase + 3 * 256) = ri1;
    }

    const int e0 = blockIdx.x * 32 + wv * 8;

    // issue first entity load NOW: hides under the barrier + RR/RI LDS reads
    v4f A0, A1, A2, A3, B0, B1, B2, B3;
    LOADE(A0, A1, A2, A3, e0);

    __syncthreads();

    const float* rbase = rot_lds + lane * 4;
    float* obase = out + (size_t)(bg * 4 + (dg & 3)) * NUM_E + e0;

    // rot fragments LDS -> registers ONCE, then PIN: the empty asm makes each
    // v4f opaque so the allocator cannot rematerialize from rot_lds. 64 VGPRs
    // stay resident for the kernel's lifetime; LDS goes quiet after this.
    v2f RR[4][4], RI[4][4];
#pragma unroll
    for (int kb = 0; kb < 4; ++kb) {
        v4f a = *(const v4f*)(rbase + (kb * 4 + 0) * 256);
        v4f b = *(const v4f*)(rbase + (kb * 4 + 1) * 256);
        v4f c = *(const v4f*)(rbase + (kb * 4 + 2) * 256);
        v4f d = *(const v4f*)(rbase + (kb * 4 + 3) * 256);
        asm("" : "+v"(a), "+v"(b), "+v"(c), "+v"(d));   // opaque pin (16 VGPRs)
        RR[kb][0] = lo2(a); RR[kb][1] = hi2(a); RR[kb][2] = lo2(b); RR[kb][3] = hi2(b);
        RI[kb][0] = lo2(c); RI[kb][1] = hi2(c); RI[kb][2] = lo2(d); RI[kb][3] = hi2(d);
    }

    const int elast = NUM_E - 1;        // prefetch clamp for the grid's last wave

#pragma unroll 1
    for (int g = 0; g < 2; ++g) {
        const int eb = e0 + g * 4;
        v4f vout;
        LOADE(B0, B1, B2, B3, eb + 1);                   // prefetch e+1
        vout[0] = dist_entity(A0, A1, A2, A3, RR, RI, dg);
        LOADE(A0, A1, A2, A3, eb + 2);                   // prefetch e+2
        vout[1] = dist_entity(B0, B1, B2, B3, RR, RI, dg);
        LOADE(B0, B1, B2, B3, eb + 3);                   // prefetch e+3
        vout[2] = dist_entity(A0, A1, A2, A3, RR, RI, dg);
        {
            int en = eb + 4; en = (en > elast) ? elast : en;
            LOADE(A0, A1, A2, A3, en);                   // prefetch next group
        }
        vout[3] = dist_entity(B0, B1, B2, B3, RR, RI, dg);
        if (dg < 4) *(v4f*)(obase + g * 4) = vout;       // 16B coalesced segment
    }
}

extern "C" void kernel_launch(void* const* d_in, const int* in_sizes, int n_in,
                              void* d_out, int out_size, void* d_ws, size_t ws_size,
                              hipStream_t stream) {
    const int*   facts = (const int*)d_in[0];
    const float* ent   = (const float*)d_in[1];
    const float* rel   = (const float*)d_in[2];
    float*       out   = (float*)d_out;
    (void)d_ws; (void)ws_size;

    // 3125 blocks x 32 entities/block = 100000 exactly
    rotate_dist_fused<<<dim3(NUM_E / 32), dim3(256), 0, stream>>>(facts, ent, rel, out);
}